// Round 5
// baseline (371.094 us; speedup 1.0000x reference)
//
#include <hip/hip_runtime.h>

// Problem constants (Attention_27668179320916)
#define Bn   2
#define Sn   512
#define DIMn 4096
#define HQn  32
#define HKVn 8
#define HDn  128
#define NPAIR 64
#define SCALE 11.313708498984761f      // scores / (hd**-0.5) == * sqrt(128) (faithful to ref)

typedef short bf16x8 __attribute__((ext_vector_type(8)));
typedef float f32x4 __attribute__((ext_vector_type(4)));
typedef unsigned short ushort8 __attribute__((ext_vector_type(8)));

__device__ __forceinline__ unsigned short f2bf_rne(float f) {
  unsigned u = __builtin_bit_cast(unsigned, f);
  u += 0x7fffu + ((u >> 16) & 1u);
  return (unsigned short)(u >> 16);
}
__device__ __forceinline__ float bf2f(unsigned short h) {
  unsigned u = ((unsigned)h) << 16;
  return __builtin_bit_cast(float, u);
}
// truncation split (round-4 in-kernel variant, used by old path + flash Q/K)
__device__ __forceinline__ void split_bf16(float x, unsigned short& hi, unsigned short& lo) {
  unsigned u = __builtin_bit_cast(unsigned, x);
  hi = (unsigned short)(u >> 16);
  float hf = __builtin_bit_cast(float, u & 0xffff0000u);
  lo = (unsigned short)(__builtin_bit_cast(unsigned, x - hf) >> 16);
}

__device__ __forceinline__ void gload16(const void* g, void* lds) {
  __builtin_amdgcn_global_load_lds(
      (const __attribute__((address_space(1))) unsigned int*)g,
      (__attribute__((address_space(3))) unsigned int*)lds, 16, 0, 0);
}

// ---------------------------------------------------------------------------
// Convert kernels: fp32 -> bf16 planes.  hi = RNE(x); lo = RNE(x - hi)
// (hi+lo accurate to ~2^-18 rel — split-GEMM quality).
// ---------------------------------------------------------------------------
__global__ void conv_split_k(const float* __restrict__ s, unsigned short* __restrict__ hi,
                             unsigned short* __restrict__ lo, int n8)
{
  for (int i = blockIdx.x * blockDim.x + threadIdx.x; i < n8; i += gridDim.x * blockDim.x) {
    float4 a = ((const float4*)s)[2 * i];
    float4 b = ((const float4*)s)[2 * i + 1];
    float xv[8] = {a.x, a.y, a.z, a.w, b.x, b.y, b.z, b.w};
    ushort8 h, l;
    #pragma unroll
    for (int j = 0; j < 8; ++j) {
      unsigned short hh = f2bf_rne(xv[j]);
      h[j] = hh;
      l[j] = f2bf_rne(xv[j] - bf2f(hh));
    }
    ((ushort8*)hi)[i] = h;
    ((ushort8*)lo)[i] = l;
  }
}
__global__ void conv_plain_k(const float* __restrict__ s, unsigned short* __restrict__ hi, int n8)
{
  for (int i = blockIdx.x * blockDim.x + threadIdx.x; i < n8; i += gridDim.x * blockDim.x) {
    float4 a = ((const float4*)s)[2 * i];
    float4 b = ((const float4*)s)[2 * i + 1];
    float xv[8] = {a.x, a.y, a.z, a.w, b.x, b.y, b.z, b.w};
    ushort8 h;
    #pragma unroll
    for (int j = 0; j < 8; ++j) h[j] = f2bf_rne(xv[j]);
    ((ushort8*)hi)[i] = h;
  }
}

// ---------------------------------------------------------------------------
// Plane GEMM: C[M,N] = A[M,Kd] * W[N,Kd]^T from pre-converted bf16 planes.
// SPLIT: hi/lo 3-MFMA (KS=32); plain: hi only, 2 k-slices (KS=64).
// BM=64, BN=128, 256 thr = 4 waves (2x2) of 32x64; LDS [2][192 rows][128B],
// 3 blocks/CU. Staging: 6x global_load_lds(16B) per thread, LINEAR dest;
// bank-spread via SOURCE-side XOR permute slot = chunk ^ (row&7), matched on
// ds_read (rule #21: swizzle both sides). One barrier per iter; next-tile
// loads issued right after the barrier so they land under this iter's MFMAs.
// ---------------------------------------------------------------------------
template<bool SPLIT, bool OUT_BF16>
__global__ __launch_bounds__(256, 3) void pgemm(
    const unsigned short* __restrict__ Ah, const unsigned short* __restrict__ Al,
    const unsigned short* __restrict__ Wh, const unsigned short* __restrict__ Wl,
    void* __restrict__ Cout, int Kd, int N)
{
  constexpr int BM = 64, BN = 128;
  constexpr int KS = SPLIT ? 32 : 64;
  __shared__ __align__(16) unsigned char Ls[2][192 * 128];

  const int t = threadIdx.x, w = t >> 6, lane = t & 63;
  const int bm = blockIdx.y * BM, bn = blockIdx.x * BN;

  // staging source pointers (LDS byte L = j*4096 + w*1024 + lane*16, linear)
  const unsigned short* gs[6];
  #pragma unroll
  for (int j = 0; j < 6; ++j) {
    int L = j * 4096 + w * 1024 + lane * 16;
    int R = L >> 7;                       // LDS row 0..191
    int slot = (L >> 4) & 7;
    int q = slot ^ (R & 7);               // inverse of read-side XOR
    int chunk = SPLIT ? (q & 3) : q;
    bool lo_ = SPLIT && (q >= 4);
    const unsigned short* base = (R < BM) ? (lo_ ? Al : Ah) : (lo_ ? Wl : Wh);
    int rg = (R < BM) ? (bm + R) : (bn + (R - BM));
    gs[j] = base + (size_t)rg * Kd + chunk * 8;
  }

  // fragment read byte offsets (hi at slot kh^(r&7); lo / slice1 at ^64)
  const int rl = lane & 15, kh = lane >> 4;
  int aoff[2], boff[4];
  #pragma unroll
  for (int fm = 0; fm < 2; ++fm) {
    int r = (w >> 1) * 32 + fm * 16 + rl;
    aoff[fm] = r * 128 + ((kh ^ (r & 7)) * 16);
  }
  #pragma unroll
  for (int fn = 0; fn < 4; ++fn) {
    int r = BM + (w & 1) * 64 + fn * 16 + rl;
    boff[fn] = r * 128 + ((kh ^ (r & 7)) * 16);
  }

  f32x4 acc[2][4];
  #pragma unroll
  for (int i = 0; i < 2; ++i)
  #pragma unroll
    for (int j = 0; j < 4; ++j) acc[i][j] = (f32x4){0.f, 0.f, 0.f, 0.f};

  const int nt = Kd / KS;
  #pragma unroll
  for (int j = 0; j < 6; ++j)                    // prologue: stage tile 0
    gload16(gs[j], &Ls[0][j * 4096 + w * 1024]);

  for (int tt = 0; tt < nt; ++tt) {
    const int buf = tt & 1;
    __syncthreads();                             // tile tt ready (vmcnt drain)
    if (tt + 1 < nt) {                           // issue next tile -> lands under MFMAs
      #pragma unroll
      for (int j = 0; j < 6; ++j)
        gload16(gs[j] + (size_t)(tt + 1) * KS, &Ls[buf ^ 1][j * 4096 + w * 1024]);
    }
    const unsigned char* Lp = &Ls[buf][0];
    bf16x8 a0[2], a1[2], b0[4], b1[4];
    #pragma unroll
    for (int fm = 0; fm < 2; ++fm) {
      a0[fm] = *(const bf16x8*)(Lp + aoff[fm]);
      a1[fm] = *(const bf16x8*)(Lp + (aoff[fm] ^ 64));
    }
    #pragma unroll
    for (int fn = 0; fn < 4; ++fn) {
      b0[fn] = *(const bf16x8*)(Lp + boff[fn]);
      b1[fn] = *(const bf16x8*)(Lp + (boff[fn] ^ 64));
    }
    #pragma unroll
    for (int fm = 0; fm < 2; ++fm)
    #pragma unroll
      for (int fn = 0; fn < 4; ++fn) {
        if constexpr (SPLIT) {
          acc[fm][fn] = __builtin_amdgcn_mfma_f32_16x16x32_bf16(a0[fm], b0[fn], acc[fm][fn], 0, 0, 0);
          acc[fm][fn] = __builtin_amdgcn_mfma_f32_16x16x32_bf16(a1[fm], b0[fn], acc[fm][fn], 0, 0, 0);
          acc[fm][fn] = __builtin_amdgcn_mfma_f32_16x16x32_bf16(a0[fm], b1[fn], acc[fm][fn], 0, 0, 0);
        } else {
          acc[fm][fn] = __builtin_amdgcn_mfma_f32_16x16x32_bf16(a0[fm], b0[fn], acc[fm][fn], 0, 0, 0);
          acc[fm][fn] = __builtin_amdgcn_mfma_f32_16x16x32_bf16(a1[fm], b1[fn], acc[fm][fn], 0, 0, 0);
        }
      }
  }

  // epilogue: C/D layout col=lane&15, row=(lane>>4)*4+reg (m89)
  const int crow0 = bm + (w >> 1) * 32 + kh * 4;
  const int ccol0 = bn + (w & 1) * 64 + rl;
  #pragma unroll
  for (int fm = 0; fm < 2; ++fm)
  #pragma unroll
    for (int fn = 0; fn < 4; ++fn)
    #pragma unroll
      for (int j = 0; j < 4; ++j) {
        size_t idx = (size_t)(crow0 + fm * 16 + j) * N + ccol0 + fn * 16;
        if constexpr (OUT_BF16) ((unsigned short*)Cout)[idx] = f2bf_rne(acc[fm][fn][j]);
        else                    ((float*)Cout)[idx] = acc[fm][fn][j];
      }
}

// ---------------------------------------------------------------------------
// Old-path MFMA GEMM (round-4, verbatim — fallback when ws is small)
// ---------------------------------------------------------------------------
template<bool SPLIT, int BN>
__global__ __launch_bounds__(256, 2) void gemm_mfma(
    const float* __restrict__ A,
    const float* __restrict__ W0, float* __restrict__ C0,
    const float* __restrict__ W1, float* __restrict__ C1,
    int Kd, int N)
{
  constexpr int BM = 64;
  constexpr int KSTEP = SPLIT ? 32 : 64;
  constexpr int CPR = SPLIT ? 4 : 8;
  constexpr int AUNITS = BM * KSTEP / 8;
  constexpr int UNITS  = (BM + BN) * KSTEP / 8;
  constexpr int UPT = UNITS / 256;
  constexpr int FN = BN / 32;
  constexpr int ROWS = BM + BN;

  __shared__ __align__(16) unsigned short Ls[2][ROWS * 64];

  const float* __restrict__ W = (blockIdx.z == 0) ? W0 : W1;
  float* __restrict__ Cp = (blockIdx.z == 0) ? C0 : C1;

  const int t  = threadIdx.x;
  const int bm = blockIdx.y * BM;
  const int bn = blockIdx.x * BN;

  const float* gsrc[UPT];
  int loff[UPT];
  #pragma unroll
  for (int i = 0; i < UPT; ++i) {
    int u = i * 256 + t;
    int row, c;
    if (u < AUNITS) {
      row = u / CPR; c = u % CPR;
      gsrc[i] = A + (size_t)(bm + row) * Kd + c * 8;
    } else {
      int v = u - AUNITS;
      int rr = v / CPR; c = v % CPR;
      row = BM + rr;
      gsrc[i] = W + (size_t)(bn + rr) * Kd + c * 8;
    }
    loff[i] = row * 64 + (c ^ (row & 7)) * 8;
  }

  const int lane = t & 63;
  const int w  = t >> 6;
  const int wr = w >> 1, wc = w & 1;
  const int rl = lane & 15, kh = lane >> 4;

  int aoff[2], boff[FN];
  #pragma unroll
  for (int fm = 0; fm < 2; ++fm) {
    int row = wr * 32 + fm * 16 + rl;
    aoff[fm] = row * 64 + (kh ^ (row & 7)) * 8;
  }
  #pragma unroll
  for (int fn = 0; fn < FN; ++fn) {
    int row = BM + wc * (BN / 2) + fn * 16 + rl;
    boff[fn] = row * 64 + (kh ^ (row & 7)) * 8;
  }

  f32x4 acc[2][FN];
  #pragma unroll
  for (int i = 0; i < 2; ++i)
  #pragma unroll
    for (int j = 0; j < FN; ++j) acc[i][j] = (f32x4){0.f, 0.f, 0.f, 0.f};

  float4 f0[UPT], f1[UPT];
  #pragma unroll
  for (int i = 0; i < UPT; ++i) {
    f0[i] = *(const float4*)(gsrc[i]);
    f1[i] = *(const float4*)(gsrc[i] + 4);
  }

  const int nt = Kd / KSTEP;
  for (int tt = 0; tt < nt; ++tt) {
    unsigned short* Lp = &Ls[tt & 1][0];
    #pragma unroll
    for (int i = 0; i < UPT; ++i) {
      float xv[8] = {f0[i].x, f0[i].y, f0[i].z, f0[i].w,
                     f1[i].x, f1[i].y, f1[i].z, f1[i].w};
      ushort8 hi, lo;
      #pragma unroll
      for (int j = 0; j < 8; ++j) {
        if constexpr (SPLIT) {
          unsigned short h_, l_;
          split_bf16(xv[j], h_, l_);
          hi[j] = h_; lo[j] = l_;
        } else {
          hi[j] = f2bf_rne(xv[j]);
          lo[j] = 0;
        }
      }
      *(ushort8*)(Lp + loff[i]) = hi;
      if constexpr (SPLIT)
        *(ushort8*)(((uintptr_t)(Lp + loff[i])) ^ 64) = lo;
    }
    if (tt + 1 < nt) {
      #pragma unroll
      for (int i = 0; i < UPT; ++i) {
        f0[i] = *(const float4*)(gsrc[i] + (size_t)(tt + 1) * KSTEP);
        f1[i] = *(const float4*)(gsrc[i] + (size_t)(tt + 1) * KSTEP + 4);
      }
    }
    __syncthreads();

    bf16x8 a0[2], a1[2], b0[FN], b1[FN];
    #pragma unroll
    for (int fm = 0; fm < 2; ++fm) {
      const unsigned short* p = Lp + aoff[fm];
      a0[fm] = *(const bf16x8*)p;
      a1[fm] = *(const bf16x8*)(((uintptr_t)p) ^ 64);
    }
    #pragma unroll
    for (int fn = 0; fn < FN; ++fn) {
      const unsigned short* p = Lp + boff[fn];
      b0[fn] = *(const bf16x8*)p;
      b1[fn] = *(const bf16x8*)(((uintptr_t)p) ^ 64);
    }
    #pragma unroll
    for (int fm = 0; fm < 2; ++fm)
    #pragma unroll
      for (int fn = 0; fn < FN; ++fn) {
        if constexpr (SPLIT) {
          acc[fm][fn] = __builtin_amdgcn_mfma_f32_16x16x32_bf16(a0[fm], b0[fn], acc[fm][fn], 0, 0, 0);
          acc[fm][fn] = __builtin_amdgcn_mfma_f32_16x16x32_bf16(a1[fm], b0[fn], acc[fm][fn], 0, 0, 0);
          acc[fm][fn] = __builtin_amdgcn_mfma_f32_16x16x32_bf16(a0[fm], b1[fn], acc[fm][fn], 0, 0, 0);
        } else {
          acc[fm][fn] = __builtin_amdgcn_mfma_f32_16x16x32_bf16(a0[fm], b0[fn], acc[fm][fn], 0, 0, 0);
          acc[fm][fn] = __builtin_amdgcn_mfma_f32_16x16x32_bf16(a1[fm], b1[fn], acc[fm][fn], 0, 0, 0);
        }
      }
  }

  const int crow0 = bm + wr * 32 + kh * 4;
  const int ccol0 = bn + wc * (BN / 2) + rl;
  #pragma unroll
  for (int fm = 0; fm < 2; ++fm)
  #pragma unroll
    for (int fn = 0; fn < FN; ++fn)
    #pragma unroll
      for (int j = 0; j < 4; ++j)
        Cp[(size_t)(crow0 + fm * 16 + j) * N + ccol0 + fn * 16] = acc[fm][fn][j];
}

// ---------------------------------------------------------------------------
// MFMA flash attention (round-4 structure, passing), templated on V/O dtype:
// BF16IO=true reads bf16 V and writes bf16 attn-out (feeds O-proj directly).
// ---------------------------------------------------------------------------
#define KT 32

template<bool BF16IO>
__global__ __launch_bounds__(256, 2) void flash_attn_mfma(
    const float* __restrict__ Qg, const float* __restrict__ Kg, const void* __restrict__ Vgv,
    const float* __restrict__ fc, const float* __restrict__ fs,
    const int* __restrict__ sidx, void* __restrict__ Ov)
{
  const int bid = blockIdx.x;
  const int qt = bid & 7;
  const int h  = (bid >> 3) & 31;
  const int b  = bid >> 8;
  const int q0 = qt * 64;
  const int hk = h >> 2;

  __shared__ __align__(16) unsigned short Ks[2][2][32][128];
  __shared__ __align__(16) unsigned short Vt[2][128][40];

  const int t = threadIdx.x;
  const int w = t >> 6;
  const int lane = t & 63;
  const int rl = lane & 15;
  const int kh = lane >> 4;

  const int qrow = q0 + w * 16 + rl;
  const int qp = sidx[qrow];

  int kr[2], kc_[2];
  #pragma unroll
  for (int i = 0; i < 2; ++i) { int u = i * 256 + t; kr[i] = u >> 4; kc_[i] = u & 15; }
  const int kkv = t >> 3, dcv = t & 7;

  const int nkt = (q0 + 64) / KT;
  const int qmaxw = q0 + w * 16 + 15;

  float kreg[2][8]; float4 kc4[2], ks4[2];
  float vregf[16];
  ushort8 vregu[2];

  #pragma unroll
  for (int i = 0; i < 2; ++i) {
    const float* kp_ = Kg + ((size_t)(b * Sn + kr[i]) * HKVn + hk) * HDn + kc_[i] * 8;
    *(float4*)&kreg[i][0] = *(const float4*)kp_;
    *(float4*)&kreg[i][4] = *(const float4*)(kp_ + 4);
    int posk = sidx[kr[i]];
    kc4[i] = *(const float4*)(fc + (size_t)posk * NPAIR + kc_[i] * 4);
    ks4[i] = *(const float4*)(fs + (size_t)posk * NPAIR + kc_[i] * 4);
  }
  if constexpr (BF16IO) {
    const unsigned short* vp_ = (const unsigned short*)Vgv +
        ((size_t)(b * Sn + kkv) * HKVn + hk) * HDn + dcv * 16;
    vregu[0] = *(const ushort8*)vp_;
    vregu[1] = *(const ushort8*)(vp_ + 8);
  } else {
    const float* vp_ = (const float*)Vgv + ((size_t)(b * Sn + kkv) * HKVn + hk) * HDn + dcv * 16;
    #pragma unroll
    for (int i = 0; i < 4; ++i) *(float4*)&vregf[i * 4] = *(const float4*)(vp_ + i * 4);
  }

  bf16x8 qh[4], ql[4];
  {
    const float* qptr = Qg + ((size_t)(b * Sn + qrow) * HQn + h) * HDn;
    #pragma unroll
    for (int ds = 0; ds < 4; ++ds) {
      int d0 = ds * 32 + kh * 8;
      float4 u0 = *(const float4*)(qptr + d0);
      float4 u1 = *(const float4*)(qptr + d0 + 4);
      float4 c4 = *(const float4*)(fc + (size_t)qp * NPAIR + d0 / 2);
      float4 s4 = *(const float4*)(fs + (size_t)qp * NPAIR + d0 / 2);
      float v[8];
      v[0] = u0.x * c4.x - u0.y * s4.x;  v[1] = u0.x * s4.x + u0.y * c4.x;
      v[2] = u0.z * c4.y - u0.w * s4.y;  v[3] = u0.z * s4.y + u0.w * c4.y;
      v[4] = u1.x * c4.z - u1.y * s4.z;  v[5] = u1.x * s4.z + u1.y * c4.z;
      v[6] = u1.z * c4.w - u1.w * s4.w;  v[7] = u1.z * s4.w + u1.w * c4.w;
      #pragma unroll
      for (int j = 0; j < 8; ++j) {
        unsigned short h_, l_;
        split_bf16(v[j], h_, l_);
        qh[ds][j] = (short)h_; ql[ds][j] = (short)l_;
      }
    }
  }

  float m_run = -3.0e38f, l_run = 0.f;
  f32x4 acc_o[8];
  #pragma unroll
  for (int i = 0; i < 8; ++i) acc_o[i] = (f32x4){0.f, 0.f, 0.f, 0.f};

  for (int tt = 0; tt < nkt; ++tt) {
    const int kbase = tt * KT;
    const int buf = tt & 1;

    #pragma unroll
    for (int i = 0; i < 2; ++i) {
      float rv[8];
      rv[0] = kreg[i][0] * kc4[i].x - kreg[i][1] * ks4[i].x;
      rv[1] = kreg[i][0] * ks4[i].x + kreg[i][1] * kc4[i].x;
      rv[2] = kreg[i][2] * kc4[i].y - kreg[i][3] * ks4[i].y;
      rv[3] = kreg[i][2] * ks4[i].y + kreg[i][3] * kc4[i].y;
      rv[4] = kreg[i][4] * kc4[i].z - kreg[i][5] * ks4[i].z;
      rv[5] = kreg[i][4] * ks4[i].z + kreg[i][5] * kc4[i].z;
      rv[6] = kreg[i][6] * kc4[i].w - kreg[i][7] * ks4[i].w;
      rv[7] = kreg[i][6] * ks4[i].w + kreg[i][7] * kc4[i].w;
      ushort8 hi, lo;
      #pragma unroll
      for (int j = 0; j < 8; ++j) {
        unsigned short h_, l_;
        split_bf16(rv[j], h_, l_);
        hi[j] = h_; lo[j] = l_;
      }
      int slot = kc_[i] ^ (kr[i] & 15);
      *(ushort8*)&Ks[buf][0][kr[i]][slot * 8] = hi;
      *(ushort8*)&Ks[buf][1][kr[i]][slot * 8] = lo;
    }
    if constexpr (BF16IO) {
      #pragma unroll
      for (int i = 0; i < 8; ++i) {
        Vt[buf][dcv * 16 + i][kkv] = vregu[0][i];
        Vt[buf][dcv * 16 + 8 + i][kkv] = vregu[1][i];
      }
    } else {
      #pragma unroll
      for (int i = 0; i < 16; ++i)
        Vt[buf][dcv * 16 + i][kkv] = f2bf_rne(vregf[i]);
    }

    if (tt + 1 < nkt) {
      const int kb = kbase + KT;
      #pragma unroll
      for (int i = 0; i < 2; ++i) {
        const float* kp_ = Kg + ((size_t)(b * Sn + kb + kr[i]) * HKVn + hk) * HDn + kc_[i] * 8;
        *(float4*)&kreg[i][0] = *(const float4*)kp_;
        *(float4*)&kreg[i][4] = *(const float4*)(kp_ + 4);
        int posk = sidx[kb + kr[i]];
        kc4[i] = *(const float4*)(fc + (size_t)posk * NPAIR + kc_[i] * 4);
        ks4[i] = *(const float4*)(fs + (size_t)posk * NPAIR + kc_[i] * 4);
      }
      if constexpr (BF16IO) {
        const unsigned short* vp_ = (const unsigned short*)Vgv +
            ((size_t)(b * Sn + kb + kkv) * HKVn + hk) * HDn + dcv * 16;
        vregu[0] = *(const ushort8*)vp_;
        vregu[1] = *(const ushort8*)(vp_ + 8);
      } else {
        const float* vp_ = (const float*)Vgv + ((size_t)(b * Sn + kb + kkv) * HKVn + hk) * HDn + dcv * 16;
        #pragma unroll
        for (int i = 0; i < 4; ++i) *(float4*)&vregf[i * 4] = *(const float4*)(vp_ + i * 4);
      }
    }
    __syncthreads();

    if (kbase > qmaxw) continue;

    float p[8];
    #pragma unroll
    for (int fm = 0; fm < 2; ++fm) {
      f32x4 accs = (f32x4){0.f, 0.f, 0.f, 0.f};
      #pragma unroll
      for (int ds = 0; ds < 4; ++ds) {
        int slot = (ds * 4 + kh) ^ rl;
        bf16x8 kH = *(const bf16x8*)&Ks[buf][0][fm * 16 + rl][slot * 8];
        bf16x8 kL = *(const bf16x8*)&Ks[buf][1][fm * 16 + rl][slot * 8];
        accs = __builtin_amdgcn_mfma_f32_16x16x32_bf16(kH, qh[ds], accs, 0, 0, 0);
        accs = __builtin_amdgcn_mfma_f32_16x16x32_bf16(kL, qh[ds], accs, 0, 0, 0);
        accs = __builtin_amdgcn_mfma_f32_16x16x32_bf16(kH, ql[ds], accs, 0, 0, 0);
      }
      #pragma unroll
      for (int r = 0; r < 4; ++r) {
        int kp = kbase + fm * 16 + kh * 4 + r;
        p[fm * 4 + r] = accs[r] * SCALE + ((kp <= qp) ? 0.f : -1.0e9f);
      }
    }

    float tmax = p[0];
    #pragma unroll
    for (int i = 1; i < 8; ++i) tmax = fmaxf(tmax, p[i]);
    tmax = fmaxf(tmax, __shfl_xor(tmax, 16));
    tmax = fmaxf(tmax, __shfl_xor(tmax, 32));
    float m_new = fmaxf(m_run, tmax);
    float crs = __expf(m_run - m_new);
    m_run = m_new;
    float tsum = 0.f;
    bf16x8 pa;
    #pragma unroll
    for (int i = 0; i < 8; ++i) {
      float ev = __expf(p[i] - m_new);
      tsum += ev;
      pa[i] = (short)f2bf_rne(ev);
    }
    tsum += __shfl_xor(tsum, 16);
    tsum += __shfl_xor(tsum, 32);
    l_run = l_run * crs + tsum;

    float cq[4];
    #pragma unroll
    for (int r = 0; r < 4; ++r) cq[r] = __shfl(crs, kh * 4 + r);

    #pragma unroll
    for (int db = 0; db < 8; ++db) {
      short4 v0 = *(const short4*)&Vt[buf][db * 16 + rl][kh * 4];
      short4 v1 = *(const short4*)&Vt[buf][db * 16 + rl][16 + kh * 4];
      bf16x8 vb = {v0.x, v0.y, v0.z, v0.w, v1.x, v1.y, v1.z, v1.w};
      f32x4 a = acc_o[db];
      a[0] *= cq[0]; a[1] *= cq[1]; a[2] *= cq[2]; a[3] *= cq[3];
      acc_o[db] = __builtin_amdgcn_mfma_f32_16x16x32_bf16(pa, vb, a, 0, 0, 0);
    }
  }

  float lq[4];
  #pragma unroll
  for (int r = 0; r < 4; ++r) lq[r] = 1.0f / __shfl(l_run, kh * 4 + r);
  #pragma unroll
  for (int db = 0; db < 8; ++db)
  #pragma unroll
    for (int r = 0; r < 4; ++r) {
      int q = q0 + w * 16 + kh * 4 + r;
      size_t idx = ((size_t)(b * Sn + q) * HQn + h) * HDn + db * 16 + rl;
      float val = acc_o[db][r] * lq[r];
      if constexpr (BF16IO) ((unsigned short*)Ov)[idx] = f2bf_rne(val);
      else                  ((float*)Ov)[idx] = val;
    }
}

// ---------------------------------------------------------------------------
extern "C" void kernel_launch(void* const* d_in, const int* in_sizes, int n_in,
                              void* d_out, int out_size, void* d_ws, size_t ws_size,
                              hipStream_t stream)
{
  const float* x    = (const float*)d_in[0];
  const float* fc   = (const float*)d_in[1];
  const float* fs   = (const float*)d_in[2];
  const int*   sidx = (const int*)d_in[5];
  const float* wq   = (const float*)d_in[6];
  const float* wk   = (const float*)d_in[7];
  const float* wv   = (const float*)d_in[8];
  const float* wo   = (const float*)d_in[9];
  float* out = (float*)d_out;

  const int M = Bn * Sn;                          // 1024
  const size_t EX = (size_t)M * DIMn;             // 4,194,304
  const size_t EW = (size_t)DIMn * DIMn;          // 16,777,216
  const size_t EK = (size_t)M * HKVn * HDn;       // 1,048,576

  // ---- new-path ws layout (bytes) ----
  char* p = (char*)d_ws;
  unsigned short* xh  = (unsigned short*)(p);                 // 2*EX
  unsigned short* xl  = (unsigned short*)(p += 2 * EX);       // 2*EX
  unsigned short* wqh = (unsigned short*)(p += 2 * EX);       // 2*EW (later: woh)
  unsigned short* wql = (unsigned short*)(p += 2 * EW);       // 2*EW (later: Aw)
  unsigned short* wkh = (unsigned short*)(p += 2 * EW);       // 2*EX
  unsigned short* wkl = (unsigned short*)(p += 2 * EX);       // 2*EX
  unsigned short* wvh = (unsigned short*)(p += 2 * EX);       // 2*EX
  float*          Qw  = (float*)(p += 2 * EX);                // 4*EX
  float*          Kw  = (float*)(p += 4 * EX);                // 4*EK
  unsigned short* Vw  = (unsigned short*)(p += 4 * EK);       // 2*EK
  const size_t NEED = (size_t)(p + 2 * EK - (char*)d_ws);

  if (ws_size >= NEED) {
    unsigned short* woh = wqh;                    // reuse after Q-proj
    unsigned short* Aw  = wql;                    // reuse after Q-proj
    // converts
    conv_split_k<<<1024, 256, 0, stream>>>(x,  xh,  xl,  (int)(EX / 8));
    conv_split_k<<<1024, 256, 0, stream>>>(wq, wqh, wql, (int)(EW / 8));
    conv_split_k<<<1024, 256, 0, stream>>>(wk, wkh, wkl, (int)(EX / 8));
    conv_plain_k<<<1024, 256, 0, stream>>>(wv, wvh, (int)(EX / 8));
    // Q-proj (split): 1024x4096x4096
    pgemm<true, false><<<dim3(DIMn / 128, M / 64), 256, 0, stream>>>(
        xh, xl, wqh, wql, Qw, DIMn, DIMn);
    // K-proj (split): 1024x1024x4096
    pgemm<true, false><<<dim3((HKVn * HDn) / 128, M / 64), 256, 0, stream>>>(
        xh, xl, wkh, wkl, Kw, DIMn, HKVn * HDn);
    // V-proj (plain, bf16 out): 1024x1024x4096
    pgemm<false, true><<<dim3((HKVn * HDn) / 128, M / 64), 256, 0, stream>>>(
        xh, xh, wvh, wvh, Vw, DIMn, HKVn * HDn);
    // wo convert (into wq_hi region, dead after Q-proj)
    conv_plain_k<<<1024, 256, 0, stream>>>(wo, woh, (int)(EW / 8));
    // flash attention (fused RoPE), bf16 V in / bf16 attn-out
    flash_attn_mfma<true><<<Bn * HQn * (Sn / 64), 256, 0, stream>>>(
        Qw, Kw, Vw, fc, fs, sidx, Aw);
    // O-proj (plain): 1024x4096x4096 -> d_out
    pgemm<false, false><<<dim3(DIMn / 128, M / 64), 256, 0, stream>>>(
        Aw, Aw, woh, woh, out, DIMn, DIMn);
  } else {
    // ---- fallback: round-4 path (40 MB ws) ----
    float* Qw2 = (float*)d_ws;
    float* Kw2 = Qw2 + (size_t)M * HQn * HDn;
    float* Vw2 = Kw2 + (size_t)M * HKVn * HDn;
    float* Aw2 = Vw2 + (size_t)M * HKVn * HDn;
    gemm_mfma<true, 128><<<dim3(DIMn / 128, M / 64, 1), 256, 0, stream>>>(
        x, wq, Qw2, wq, Qw2, DIMn, DIMn);
    gemm_mfma<true, 64><<<dim3((HKVn * HDn) / 64, M / 64, 2), 256, 0, stream>>>(
        x, wk, Kw2, wv, Vw2, DIMn, HKVn * HDn);
    flash_attn_mfma<false><<<Bn * HQn * (Sn / 64), 256, 0, stream>>>(
        Qw2, Kw2, Vw2, fc, fs, sidx, Aw2);
    gemm_mfma<false, 128><<<dim3(DIMn / 128, M / 64, 1), 256, 0, stream>>>(
        Aw2, wo, out, wo, out, DIMn, DIMn);
  }
}

// Round 6
// 315.246 us; speedup vs baseline: 1.1772x; 1.1772x over previous
//
#include <hip/hip_runtime.h>

// Problem constants (Attention_27668179320916)
#define Bn   2
#define Sn   512
#define DIMn 4096
#define HQn  32
#define HKVn 8
#define HDn  128
#define NPAIR 64
#define KVN  (HKVn * HDn)              // 1024
#define SCALE 11.313708498984761f      // scores / (hd**-0.5) == * sqrt(128) (faithful to ref)

typedef short bf16x8 __attribute__((ext_vector_type(8)));
typedef float f32x4 __attribute__((ext_vector_type(4)));
typedef unsigned short ushort8 __attribute__((ext_vector_type(8)));

__device__ __forceinline__ unsigned short f2bf_rne(float f) {
  unsigned u = __builtin_bit_cast(unsigned, f);
  u += 0x7fffu + ((u >> 16) & 1u);
  return (unsigned short)(u >> 16);
}
__device__ __forceinline__ float bf2f(unsigned short h) {
  unsigned u = ((unsigned)h) << 16;
  return __builtin_bit_cast(float, u);
}
// trunc split (flash Q/K + fallback path)
__device__ __forceinline__ void split_bf16(float x, unsigned short& hi, unsigned short& lo) {
  unsigned u = __builtin_bit_cast(unsigned, x);
  hi = (unsigned short)(u >> 16);
  float hf = __builtin_bit_cast(float, u & 0xffff0000u);
  lo = (unsigned short)(__builtin_bit_cast(unsigned, x - hf) >> 16);
}
__device__ __forceinline__ void gload16(const void* g, void* lds) {
  __builtin_amdgcn_global_load_lds(
      (const __attribute__((address_space(1))) unsigned int*)g,
      (__attribute__((address_space(3))) unsigned int*)lds, 16, 0, 0);
}

// ---------------------------------------------------------------------------
// Fused convert: x/wq/wk/wv fp32 -> split bf16 planes (hi=RNE, lo=RNE residual)
// wk,wv land in ONE contiguous wkv plane (rows 0..1023 = wk, 1024..2047 = wv).
// ---------------------------------------------------------------------------
__global__ void conv_all_k(const float* __restrict__ x,  const float* __restrict__ wq,
                           const float* __restrict__ wk, const float* __restrict__ wv,
                           unsigned short* __restrict__ xh,   unsigned short* __restrict__ xl,
                           unsigned short* __restrict__ wqh,  unsigned short* __restrict__ wql,
                           unsigned short* __restrict__ wkvh, unsigned short* __restrict__ wkvl)
{
  constexpr int XU = (Bn * Sn * DIMn) / 8;   // 524288
  constexpr int QU = (DIMn * DIMn) / 8;      // 2097152
  constexpr int KU = (KVN * DIMn) / 8;       // 524288
  constexpr int TOT = XU + QU + KU + KU;
  constexpr size_t VOFF = (size_t)KVN * DIMn / 8;   // wv unit offset inside wkv planes
  for (int u = blockIdx.x * blockDim.x + threadIdx.x; u < TOT; u += gridDim.x * blockDim.x) {
    const float* s; unsigned short* ph; unsigned short* pl; size_t i;
    if (u < XU)                { s = x;  ph = xh;   pl = xl;   i = u; }
    else if (u < XU + QU)      { s = wq; ph = wqh;  pl = wql;  i = u - XU; }
    else if (u < XU + QU + KU) { s = wk; ph = wkvh; pl = wkvl; i = u - (XU + QU); }
    else { s = wv; ph = wkvh; pl = wkvl; i = (size_t)(u - (XU + QU + KU)) + VOFF; }
    float4 a = ((const float4*)s)[2 * (i - (s == wv ? VOFF : 0)) ];
    // NOTE: source index must not include VOFF — recompute cleanly:
    size_t si = (s == wv) ? (i - VOFF) : i;
    a = ((const float4*)s)[2 * si];
    float4 b = ((const float4*)s)[2 * si + 1];
    float xv[8] = {a.x, a.y, a.z, a.w, b.x, b.y, b.z, b.w};
    ushort8 h, l;
    #pragma unroll
    for (int j = 0; j < 8; ++j) {
      unsigned short hh = f2bf_rne(xv[j]);
      h[j] = hh;
      l[j] = f2bf_rne(xv[j] - bf2f(hh));
    }
    ((ushort8*)ph)[i] = h;
    ((ushort8*)pl)[i] = l;
  }
}
__global__ void conv_plain_k(const float* __restrict__ s, unsigned short* __restrict__ hi, int n8)
{
  for (int i = blockIdx.x * blockDim.x + threadIdx.x; i < n8; i += gridDim.x * blockDim.x) {
    float4 a = ((const float4*)s)[2 * i];
    float4 b = ((const float4*)s)[2 * i + 1];
    float xv[8] = {a.x, a.y, a.z, a.w, b.x, b.y, b.z, b.w};
    ushort8 h;
    #pragma unroll
    for (int j = 0; j < 8; ++j) h[j] = f2bf_rne(xv[j]);
    ((ushort8*)hi)[i] = h;
  }
}

// ---------------------------------------------------------------------------
// Deep-pipelined plane GEMM v2: C = A[M,Kd] * W[N,Kd]^T from bf16 planes.
// FM: M-frags per wave (4 -> BM=128 wave 64x64; 2 -> BM=64 wave 32x64). BN=128.
// SPLIT: hi/lo 3-MFMA (KS=32); plain: hi 2 k-slices (KS=64).
// 3 LDS buffers, counted-vmcnt pipeline (T3/T4): per iter
//   s_waitcnt vmcnt(UPT)  (tile t's loads done; t+1's stay IN FLIGHT)
//   s_barrier + sched_barrier(0)
//   issue tile t+2 gloads -> buf[(t+2)%3]; ds_read + MFMA from buf[t%3]
// Hazard proof (depth 3): buf[(t+2)%3]==buf[(t-1)%3]; tile t-1's ds_reads
// completed before barrier(t) because their MFMAs consumed them (lgkm waits),
// and all waves passed barrier(t) before any t+2 gload issues.
// Bank-spread: linear gload dest + source XOR permute q=slot^(R&7), matched
// on read (rule #21) — measured 0 conflicts in round 5.
// OMODE: 0 = fp32 out, 1 = bf16 out, 2 = K/V mixed (col<1024 -> fp32 C0,
// else bf16 C1 at col-1024; ld = KVN).
// ---------------------------------------------------------------------------
template<bool SPLIT, int FM, int OMODE>
__global__ __launch_bounds__(256, (FM == 4) ? 1 : 2) void pgemm2(
    const unsigned short* __restrict__ Ah, const unsigned short* __restrict__ Al,
    const unsigned short* __restrict__ Wh, const unsigned short* __restrict__ Wl,
    void* __restrict__ C0, void* __restrict__ C1, int Kd, int NLD)
{
  constexpr int BM = 32 * FM;
  constexpr int ROWS = BM + 128;
  constexpr int UPT = ROWS / 32;             // gloads per thread per tile (8 or 6)
  constexpr int KS = SPLIT ? 32 : 64;
  constexpr int TILEB = ROWS * 128;

  __shared__ __align__(16) unsigned char Ls[3 * TILEB];

  const int t = threadIdx.x, w = t >> 6, lane = t & 63;
  const int bm = blockIdx.y * BM, bn = blockIdx.x * 128;

  // staging descriptors: unit u = j*256+t covers LDS bytes [u*16, u*16+16)
  const unsigned short* gsrc[UPT];
  #pragma unroll
  for (int j = 0; j < UPT; ++j) {
    int u = j * 256 + t;
    int R = u >> 3;                          // LDS row
    int q = (u & 7) ^ (R & 7);               // source chunk id (XOR permute)
    int chunk = SPLIT ? (q & 3) : q;
    bool lo_ = SPLIT && (q >= 4);
    const unsigned short* base = (R < BM) ? (lo_ ? Al : Ah) : (lo_ ? Wl : Wh);
    int rg = (R < BM) ? (bm + R) : (bn + (R - BM));
    gsrc[j] = base + (size_t)rg * Kd + chunk * 8;
  }

  // fragment read byte offsets
  const int wr = w >> 1, wc = w & 1;
  const int rl = lane & 15, kh = lane >> 4;
  int aoff[FM], boff[4];
  #pragma unroll
  for (int fm = 0; fm < FM; ++fm) {
    int r = wr * (16 * FM) + fm * 16 + rl;
    aoff[fm] = r * 128 + ((kh ^ (r & 7)) * 16);
  }
  #pragma unroll
  for (int fn = 0; fn < 4; ++fn) {
    int r = BM + wc * 64 + fn * 16 + rl;
    boff[fn] = r * 128 + ((kh ^ (r & 7)) * 16);
  }

  f32x4 acc[FM][4];
  #pragma unroll
  for (int i = 0; i < FM; ++i)
  #pragma unroll
    for (int j = 0; j < 4; ++j) acc[i][j] = (f32x4){0.f, 0.f, 0.f, 0.f};

  const int nt = Kd / KS;
  // prologue: stage tiles 0 and 1
  #pragma unroll
  for (int j = 0; j < UPT; ++j) gload16(gsrc[j], &Ls[0 * TILEB + (j * 256 + t) * 16]);
  #pragma unroll
  for (int j = 0; j < UPT; ++j) gload16(gsrc[j] + KS, &Ls[1 * TILEB + (j * 256 + t) * 16]);

  int cur = 0;
  for (int tt = 0; tt < nt; ++tt) {
    if (tt + 1 < nt) asm volatile("s_waitcnt vmcnt(%0)" :: "n"(UPT) : "memory");
    else             asm volatile("s_waitcnt vmcnt(0)" ::: "memory");
    __builtin_amdgcn_s_barrier();
    __builtin_amdgcn_sched_barrier(0);

    int pre = cur + 2; if (pre >= 3) pre -= 3;
    if (tt + 2 < nt) {
      #pragma unroll
      for (int j = 0; j < UPT; ++j)
        gload16(gsrc[j] + (size_t)(tt + 2) * KS, &Ls[pre * TILEB + (j * 256 + t) * 16]);
    }

    const unsigned char* Lp = &Ls[cur * TILEB];
    bf16x8 a0[FM], a1[FM], b0[4], b1[4];
    #pragma unroll
    for (int fm = 0; fm < FM; ++fm) {
      a0[fm] = *(const bf16x8*)(Lp + aoff[fm]);
      a1[fm] = *(const bf16x8*)(Lp + (aoff[fm] ^ 64));   // lo (split) / k-slice1 (plain)
    }
    #pragma unroll
    for (int fn = 0; fn < 4; ++fn) {
      b0[fn] = *(const bf16x8*)(Lp + boff[fn]);
      b1[fn] = *(const bf16x8*)(Lp + (boff[fn] ^ 64));
    }
    #pragma unroll
    for (int fm = 0; fm < FM; ++fm)
    #pragma unroll
      for (int fn = 0; fn < 4; ++fn) {
        if constexpr (SPLIT) {
          acc[fm][fn] = __builtin_amdgcn_mfma_f32_16x16x32_bf16(a0[fm], b0[fn], acc[fm][fn], 0, 0, 0);
          acc[fm][fn] = __builtin_amdgcn_mfma_f32_16x16x32_bf16(a1[fm], b0[fn], acc[fm][fn], 0, 0, 0);
          acc[fm][fn] = __builtin_amdgcn_mfma_f32_16x16x32_bf16(a0[fm], b1[fn], acc[fm][fn], 0, 0, 0);
        } else {
          acc[fm][fn] = __builtin_amdgcn_mfma_f32_16x16x32_bf16(a0[fm], b0[fn], acc[fm][fn], 0, 0, 0);
          acc[fm][fn] = __builtin_amdgcn_mfma_f32_16x16x32_bf16(a1[fm], b1[fn], acc[fm][fn], 0, 0, 0);
        }
      }
    cur += 1; if (cur >= 3) cur -= 3;
  }

  // epilogue: C/D layout col=lane&15, row=(lane>>4)*4+reg (m89)
  const int crow0 = bm + wr * (16 * FM) + kh * 4;
  #pragma unroll
  for (int fm = 0; fm < FM; ++fm)
  #pragma unroll
    for (int fn = 0; fn < 4; ++fn)
    #pragma unroll
      for (int j = 0; j < 4; ++j) {
        int row = crow0 + fm * 16 + j;
        float v = acc[fm][fn][j];
        if constexpr (OMODE == 0) {
          int col = bn + wc * 64 + fn * 16 + rl;
          ((float*)C0)[(size_t)row * NLD + col] = v;
        } else if constexpr (OMODE == 1) {
          int col = bn + wc * 64 + fn * 16 + rl;
          ((unsigned short*)C0)[(size_t)row * NLD + col] = f2bf_rne(v);
        } else {
          int col = (bn & (KVN - 1)) + wc * 64 + fn * 16 + rl;
          if (bn < KVN) ((float*)C0)[(size_t)row * KVN + col] = v;
          else ((unsigned short*)C1)[(size_t)row * KVN + col] = f2bf_rne(v);
        }
      }
}

// ---------------------------------------------------------------------------
// Fallback GEMM (round-4, verbatim) — used only if ws_size is small.
// ---------------------------------------------------------------------------
template<bool SPLIT, int BN>
__global__ __launch_bounds__(256, 2) void gemm_mfma(
    const float* __restrict__ A,
    const float* __restrict__ W0, float* __restrict__ C0,
    const float* __restrict__ W1, float* __restrict__ C1,
    int Kd, int N)
{
  constexpr int BM = 64;
  constexpr int KSTEP = SPLIT ? 32 : 64;
  constexpr int CPR = SPLIT ? 4 : 8;
  constexpr int AUNITS = BM * KSTEP / 8;
  constexpr int UNITS  = (BM + BN) * KSTEP / 8;
  constexpr int UPT = UNITS / 256;
  constexpr int FN = BN / 32;
  constexpr int ROWS = BM + BN;

  __shared__ __align__(16) unsigned short Ls[2][ROWS * 64];

  const float* __restrict__ W = (blockIdx.z == 0) ? W0 : W1;
  float* __restrict__ Cp = (blockIdx.z == 0) ? C0 : C1;

  const int t  = threadIdx.x;
  const int bm = blockIdx.y * BM;
  const int bn = blockIdx.x * BN;

  const float* gsrc[UPT];
  int loff[UPT];
  #pragma unroll
  for (int i = 0; i < UPT; ++i) {
    int u = i * 256 + t;
    int row, c;
    if (u < AUNITS) {
      row = u / CPR; c = u % CPR;
      gsrc[i] = A + (size_t)(bm + row) * Kd + c * 8;
    } else {
      int v = u - AUNITS;
      int rr = v / CPR; c = v % CPR;
      row = BM + rr;
      gsrc[i] = W + (size_t)(bn + rr) * Kd + c * 8;
    }
    loff[i] = row * 64 + (c ^ (row & 7)) * 8;
  }

  const int lane = t & 63;
  const int w  = t >> 6;
  const int wr = w >> 1, wc = w & 1;
  const int rl = lane & 15, kh = lane >> 4;

  int aoff[2], boff[FN];
  #pragma unroll
  for (int fm = 0; fm < 2; ++fm) {
    int row = wr * 32 + fm * 16 + rl;
    aoff[fm] = row * 64 + (kh ^ (row & 7)) * 8;
  }
  #pragma unroll
  for (int fn = 0; fn < FN; ++fn) {
    int row = BM + wc * (BN / 2) + fn * 16 + rl;
    boff[fn] = row * 64 + (kh ^ (row & 7)) * 8;
  }

  f32x4 acc[2][FN];
  #pragma unroll
  for (int i = 0; i < 2; ++i)
  #pragma unroll
    for (int j = 0; j < FN; ++j) acc[i][j] = (f32x4){0.f, 0.f, 0.f, 0.f};

  float4 f0[UPT], f1[UPT];
  #pragma unroll
  for (int i = 0; i < UPT; ++i) {
    f0[i] = *(const float4*)(gsrc[i]);
    f1[i] = *(const float4*)(gsrc[i] + 4);
  }

  const int nt = Kd / KSTEP;
  for (int tt = 0; tt < nt; ++tt) {
    unsigned short* Lp = &Ls[tt & 1][0];
    #pragma unroll
    for (int i = 0; i < UPT; ++i) {
      float xv[8] = {f0[i].x, f0[i].y, f0[i].z, f0[i].w,
                     f1[i].x, f1[i].y, f1[i].z, f1[i].w};
      ushort8 hi, lo;
      #pragma unroll
      for (int j = 0; j < 8; ++j) {
        if constexpr (SPLIT) {
          unsigned short h_, l_;
          split_bf16(xv[j], h_, l_);
          hi[j] = h_; lo[j] = l_;
        } else {
          hi[j] = f2bf_rne(xv[j]);
          lo[j] = 0;
        }
      }
      *(ushort8*)(Lp + loff[i]) = hi;
      if constexpr (SPLIT)
        *(ushort8*)(((uintptr_t)(Lp + loff[i])) ^ 64) = lo;
    }
    if (tt + 1 < nt) {
      #pragma unroll
      for (int i = 0; i < UPT; ++i) {
        f0[i] = *(const float4*)(gsrc[i] + (size_t)(tt + 1) * KSTEP);
        f1[i] = *(const float4*)(gsrc[i] + (size_t)(tt + 1) * KSTEP + 4);
      }
    }
    __syncthreads();

    bf16x8 a0[2], a1[2], b0[FN], b1[FN];
    #pragma unroll
    for (int fm = 0; fm < 2; ++fm) {
      const unsigned short* p = Lp + aoff[fm];
      a0[fm] = *(const bf16x8*)p;
      a1[fm] = *(const bf16x8*)(((uintptr_t)p) ^ 64);
    }
    #pragma unroll
    for (int fn = 0; fn < FN; ++fn) {
      const unsigned short* p = Lp + boff[fn];
      b0[fn] = *(const bf16x8*)p;
      b1[fn] = *(const bf16x8*)(((uintptr_t)p) ^ 64);
    }
    #pragma unroll
    for (int fm = 0; fm < 2; ++fm)
    #pragma unroll
      for (int fn = 0; fn < FN; ++fn) {
        if constexpr (SPLIT) {
          acc[fm][fn] = __builtin_amdgcn_mfma_f32_16x16x32_bf16(a0[fm], b0[fn], acc[fm][fn], 0, 0, 0);
          acc[fm][fn] = __builtin_amdgcn_mfma_f32_16x16x32_bf16(a1[fm], b0[fn], acc[fm][fn], 0, 0, 0);
          acc[fm][fn] = __builtin_amdgcn_mfma_f32_16x16x32_bf16(a0[fm], b1[fn], acc[fm][fn], 0, 0, 0);
        } else {
          acc[fm][fn] = __builtin_amdgcn_mfma_f32_16x16x32_bf16(a0[fm], b0[fn], acc[fm][fn], 0, 0, 0);
          acc[fm][fn] = __builtin_amdgcn_mfma_f32_16x16x32_bf16(a1[fm], b1[fn], acc[fm][fn], 0, 0, 0);
        }
      }
  }

  const int crow0 = bm + wr * 32 + kh * 4;
  const int ccol0 = bn + wc * (BN / 2) + rl;
  #pragma unroll
  for (int fm = 0; fm < 2; ++fm)
  #pragma unroll
    for (int fn = 0; fn < FN; ++fn)
    #pragma unroll
      for (int j = 0; j < 4; ++j)
        Cp[(size_t)(crow0 + fm * 16 + j) * N + ccol0 + fn * 16] = acc[fm][fn][j];
}

// ---------------------------------------------------------------------------
// MFMA flash attention (round-4/5 structure, passing). BF16IO: bf16 V in,
// bf16 attn-out. Masked scores underflow to exactly 0; stale cache always
// masked => cache/mask tensors never read.
// ---------------------------------------------------------------------------
#define KT 32

template<bool BF16IO>
__global__ __launch_bounds__(256, 2) void flash_attn_mfma(
    const float* __restrict__ Qg, const float* __restrict__ Kg, const void* __restrict__ Vgv,
    const float* __restrict__ fc, const float* __restrict__ fs,
    const int* __restrict__ sidx, void* __restrict__ Ov)
{
  const int bid = blockIdx.x;
  const int qt = bid & 7;
  const int h  = (bid >> 3) & 31;
  const int b  = bid >> 8;
  const int q0 = qt * 64;
  const int hk = h >> 2;

  __shared__ __align__(16) unsigned short Ks[2][2][32][128];
  __shared__ __align__(16) unsigned short Vt[2][128][40];

  const int t = threadIdx.x;
  const int w = t >> 6;
  const int lane = t & 63;
  const int rl = lane & 15;
  const int kh = lane >> 4;

  const int qrow = q0 + w * 16 + rl;
  const int qp = sidx[qrow];

  int kr[2], kc_[2];
  #pragma unroll
  for (int i = 0; i < 2; ++i) { int u = i * 256 + t; kr[i] = u >> 4; kc_[i] = u & 15; }
  const int kkv = t >> 3, dcv = t & 7;

  const int nkt = (q0 + 64) / KT;
  const int qmaxw = q0 + w * 16 + 15;

  float kreg[2][8]; float4 kc4[2], ks4[2];
  float vregf[16];
  ushort8 vregu[2];

  #pragma unroll
  for (int i = 0; i < 2; ++i) {
    const float* kp_ = Kg + ((size_t)(b * Sn + kr[i]) * HKVn + hk) * HDn + kc_[i] * 8;
    *(float4*)&kreg[i][0] = *(const float4*)kp_;
    *(float4*)&kreg[i][4] = *(const float4*)(kp_ + 4);
    int posk = sidx[kr[i]];
    kc4[i] = *(const float4*)(fc + (size_t)posk * NPAIR + kc_[i] * 4);
    ks4[i] = *(const float4*)(fs + (size_t)posk * NPAIR + kc_[i] * 4);
  }
  if constexpr (BF16IO) {
    const unsigned short* vp_ = (const unsigned short*)Vgv +
        ((size_t)(b * Sn + kkv) * HKVn + hk) * HDn + dcv * 16;
    vregu[0] = *(const ushort8*)vp_;
    vregu[1] = *(const ushort8*)(vp_ + 8);
  } else {
    const float* vp_ = (const float*)Vgv + ((size_t)(b * Sn + kkv) * HKVn + hk) * HDn + dcv * 16;
    #pragma unroll
    for (int i = 0; i < 4; ++i) *(float4*)&vregf[i * 4] = *(const float4*)(vp_ + i * 4);
  }

  bf16x8 qh[4], ql[4];
  {
    const float* qptr = Qg + ((size_t)(b * Sn + qrow) * HQn + h) * HDn;
    #pragma unroll
    for (int ds = 0; ds < 4; ++ds) {
      int d0 = ds * 32 + kh * 8;
      float4 u0 = *(const float4*)(qptr + d0);
      float4 u1 = *(const float4*)(qptr + d0 + 4);
      float4 c4 = *(const float4*)(fc + (size_t)qp * NPAIR + d0 / 2);
      float4 s4 = *(const float4*)(fs + (size_t)qp * NPAIR + d0 / 2);
      float v[8];
      v[0] = u0.x * c4.x - u0.y * s4.x;  v[1] = u0.x * s4.x + u0.y * c4.x;
      v[2] = u0.z * c4.y - u0.w * s4.y;  v[3] = u0.z * s4.y + u0.w * c4.y;
      v[4] = u1.x * c4.z - u1.y * s4.z;  v[5] = u1.x * s4.z + u1.y * c4.z;
      v[6] = u1.z * c4.w - u1.w * s4.w;  v[7] = u1.z * s4.w + u1.w * c4.w;
      #pragma unroll
      for (int j = 0; j < 8; ++j) {
        unsigned short h_, l_;
        split_bf16(v[j], h_, l_);
        qh[ds][j] = (short)h_; ql[ds][j] = (short)l_;
      }
    }
  }

  float m_run = -3.0e38f, l_run = 0.f;
  f32x4 acc_o[8];
  #pragma unroll
  for (int i = 0; i < 8; ++i) acc_o[i] = (f32x4){0.f, 0.f, 0.f, 0.f};

  for (int tt = 0; tt < nkt; ++tt) {
    const int kbase = tt * KT;
    const int buf = tt & 1;

    #pragma unroll
    for (int i = 0; i < 2; ++i) {
      float rv[8];
      rv[0] = kreg[i][0] * kc4[i].x - kreg[i][1] * ks4[i].x;
      rv[1] = kreg[i][0] * ks4[i].x + kreg[i][1] * kc4[i].x;
      rv[2] = kreg[i][2] * kc4[i].y - kreg[i][3] * ks4[i].y;
      rv[3] = kreg[i][2] * ks4[i].y + kreg[i][3] * kc4[i].y;
      rv[4] = kreg[i][4] * kc4[i].z - kreg[i][5] * ks4[i].z;
      rv[5] = kreg[i][4] * ks4[i].z + kreg[i][5] * kc4[i].z;
      rv[6] = kreg[i][6] * kc4[i].w - kreg[i][7] * ks4[i].w;
      rv[7] = kreg[i][6] * ks4[i].w + kreg[i][7] * kc4[i].w;
      ushort8 hi, lo;
      #pragma unroll
      for (int j = 0; j < 8; ++j) {
        unsigned short h_, l_;
        split_bf16(rv[j], h_, l_);
        hi[j] = h_; lo[j] = l_;
      }
      int slot = kc_[i] ^ (kr[i] & 15);
      *(ushort8*)&Ks[buf][0][kr[i]][slot * 8] = hi;
      *(ushort8*)&Ks[buf][1][kr[i]][slot * 8] = lo;
    }
    if constexpr (BF16IO) {
      #pragma unroll
      for (int i = 0; i < 8; ++i) {
        Vt[buf][dcv * 16 + i][kkv] = vregu[0][i];
        Vt[buf][dcv * 16 + 8 + i][kkv] = vregu[1][i];
      }
    } else {
      #pragma unroll
      for (int i = 0; i < 16; ++i)
        Vt[buf][dcv * 16 + i][kkv] = f2bf_rne(vregf[i]);
    }

    if (tt + 1 < nkt) {
      const int kb = kbase + KT;
      #pragma unroll
      for (int i = 0; i < 2; ++i) {
        const float* kp_ = Kg + ((size_t)(b * Sn + kb + kr[i]) * HKVn + hk) * HDn + kc_[i] * 8;
        *(float4*)&kreg[i][0] = *(const float4*)kp_;
        *(float4*)&kreg[i][4] = *(const float4*)(kp_ + 4);
        int posk = sidx[kb + kr[i]];
        kc4[i] = *(const float4*)(fc + (size_t)posk * NPAIR + kc_[i] * 4);
        ks4[i] = *(const float4*)(fs + (size_t)posk * NPAIR + kc_[i] * 4);
      }
      if constexpr (BF16IO) {
        const unsigned short* vp_ = (const unsigned short*)Vgv +
            ((size_t)(b * Sn + kb + kkv) * HKVn + hk) * HDn + dcv * 16;
        vregu[0] = *(const ushort8*)vp_;
        vregu[1] = *(const ushort8*)(vp_ + 8);
      } else {
        const float* vp_ = (const float*)Vgv + ((size_t)(b * Sn + kb + kkv) * HKVn + hk) * HDn + dcv * 16;
        #pragma unroll
        for (int i = 0; i < 4; ++i) *(float4*)&vregf[i * 4] = *(const float4*)(vp_ + i * 4);
      }
    }
    __syncthreads();

    if (kbase > qmaxw) continue;

    float p[8];
    #pragma unroll
    for (int fm = 0; fm < 2; ++fm) {
      f32x4 accs = (f32x4){0.f, 0.f, 0.f, 0.f};
      #pragma unroll
      for (int ds = 0; ds < 4; ++ds) {
        int slot = (ds * 4 + kh) ^ rl;
        bf16x8 kH = *(const bf16x8*)&Ks[buf][0][fm * 16 + rl][slot * 8];
        bf16x8 kL = *(const bf16x8*)&Ks[buf][1][fm * 16 + rl][slot * 8];
        accs = __builtin_amdgcn_mfma_f32_16x16x32_bf16(kH, qh[ds], accs, 0, 0, 0);
        accs = __builtin_amdgcn_mfma_f32_16x16x32_bf16(kL, qh[ds], accs, 0, 0, 0);
        accs = __builtin_amdgcn_mfma_f32_16x16x32_bf16(kH, ql[ds], accs, 0, 0, 0);
      }
      #pragma unroll
      for (int r = 0; r < 4; ++r) {
        int kp = kbase + fm * 16 + kh * 4 + r;
        p[fm * 4 + r] = accs[r] * SCALE + ((kp <= qp) ? 0.f : -1.0e9f);
      }
    }

    float tmax = p[0];
    #pragma unroll
    for (int i = 1; i < 8; ++i) tmax = fmaxf(tmax, p[i]);
    tmax = fmaxf(tmax, __shfl_xor(tmax, 16));
    tmax = fmaxf(tmax, __shfl_xor(tmax, 32));
    float m_new = fmaxf(m_run, tmax);
    float crs = __expf(m_run - m_new);
    m_run = m_new;
    float tsum = 0.f;
    bf16x8 pa;
    #pragma unroll
    for (int i = 0; i < 8; ++i) {
      float ev = __expf(p[i] - m_new);
      tsum += ev;
      pa[i] = (short)f2bf_rne(ev);
    }
    tsum += __shfl_xor(tsum, 16);
    tsum += __shfl_xor(tsum, 32);
    l_run = l_run * crs + tsum;

    float cq[4];
    #pragma unroll
    for (int r = 0; r < 4; ++r) cq[r] = __shfl(crs, kh * 4 + r);

    #pragma unroll
    for (int db = 0; db < 8; ++db) {
      short4 v0 = *(const short4*)&Vt[buf][db * 16 + rl][kh * 4];
      short4 v1 = *(const short4*)&Vt[buf][db * 16 + rl][16 + kh * 4];
      bf16x8 vb = {v0.x, v0.y, v0.z, v0.w, v1.x, v1.y, v1.z, v1.w};
      f32x4 a = acc_o[db];
      a[0] *= cq[0]; a[1] *= cq[1]; a[2] *= cq[2]; a[3] *= cq[3];
      acc_o[db] = __builtin_amdgcn_mfma_f32_16x16x32_bf16(pa, vb, a, 0, 0, 0);
    }
  }

  float lq[4];
  #pragma unroll
  for (int r = 0; r < 4; ++r) lq[r] = 1.0f / __shfl(l_run, kh * 4 + r);
  #pragma unroll
  for (int db = 0; db < 8; ++db)
  #pragma unroll
    for (int r = 0; r < 4; ++r) {
      int q = q0 + w * 16 + kh * 4 + r;
      size_t idx = ((size_t)(b * Sn + q) * HQn + h) * HDn + db * 16 + rl;
      float val = acc_o[db][r] * lq[r];
      if constexpr (BF16IO) ((unsigned short*)Ov)[idx] = f2bf_rne(val);
      else                  ((float*)Ov)[idx] = val;
    }
}

// ---------------------------------------------------------------------------
extern "C" void kernel_launch(void* const* d_in, const int* in_sizes, int n_in,
                              void* d_out, int out_size, void* d_ws, size_t ws_size,
                              hipStream_t stream)
{
  const float* x    = (const float*)d_in[0];
  const float* fc   = (const float*)d_in[1];
  const float* fs   = (const float*)d_in[2];
  const int*   sidx = (const int*)d_in[5];
  const float* wq   = (const float*)d_in[6];
  const float* wk   = (const float*)d_in[7];
  const float* wv   = (const float*)d_in[8];
  const float* wo   = (const float*)d_in[9];
  float* out = (float*)d_out;

  const int M = Bn * Sn;                          // 1024
  const size_t EX  = (size_t)M * DIMn;            // 4,194,304
  const size_t EW  = (size_t)DIMn * DIMn;         // 16,777,216
  const size_t EKV = (size_t)2 * KVN * DIMn;      // 8,388,608
  const size_t EK  = (size_t)M * KVN;             // 1,048,576

  char* p = (char*)d_ws;
  unsigned short* xh   = (unsigned short*)(p);
  unsigned short* xl   = (unsigned short*)(p += 2 * EX);
  unsigned short* wqh  = (unsigned short*)(p += 2 * EX);
  unsigned short* wql  = (unsigned short*)(p += 2 * EW);
  unsigned short* wkvh = (unsigned short*)(p += 2 * EW);
  unsigned short* wkvl = (unsigned short*)(p += 2 * EKV);
  float*          Qw   = (float*)(p += 2 * EKV);
  float*          Kw   = (float*)(p += 4 * EX);
  unsigned short* Vw   = (unsigned short*)(p += 4 * EK);
  const size_t NEED = (size_t)((char*)Vw + 2 * EK - (char*)d_ws);   // ~141 MB

  if (ws_size >= NEED) {
    unsigned short* woh = wql;                    // dead after Q-proj
    unsigned short* Aw  = wqh;                    // dead after Q-proj
    // converts (x, wq, wkv split) — one fused launch
    conv_all_k<<<2048, 256, 0, stream>>>(x, wq, wk, wv, xh, xl, wqh, wql, wkvh, wkvl);
    // Q-proj (split, 64x64 waves): 1024x4096x4096, grid 256 (1/CU), 3-buf vmcnt pipe
    pgemm2<true, 4, 0><<<dim3(DIMn / 128, M / 128), 256, 0, stream>>>(
        xh, xl, wqh, wql, Qw, nullptr, DIMn, DIMn);
    // wo convert into wql region
    conv_plain_k<<<1024, 256, 0, stream>>>(wo, woh, (int)(EW / 8));
    // K+V fused (split, 32x64 waves, mixed epilogue): 1024x2048x4096, grid 256
    pgemm2<true, 2, 2><<<dim3((2 * KVN) / 128, M / 64), 256, 0, stream>>>(
        xh, xl, wkvh, wkvl, Kw, Vw, DIMn, KVN);
    // flash attention (fused RoPE), bf16 V in / bf16 attn-out
    flash_attn_mfma<true><<<Bn * HQn * (Sn / 64), 256, 0, stream>>>(
        Qw, Kw, Vw, fc, fs, sidx, Aw);
    // O-proj (plain, 64x64 waves): 1024x4096x4096 -> d_out
    pgemm2<false, 4, 0><<<dim3(DIMn / 128, M / 128), 256, 0, stream>>>(
        Aw, Aw, woh, woh, out, nullptr, DIMn, DIMn);
  } else {
    // fallback: round-4 path (40 MB ws)
    float* Qw2 = (float*)d_ws;
    float* Kw2 = Qw2 + (size_t)M * HQn * HDn;
    float* Vw2 = Kw2 + (size_t)M * HKVn * HDn;
    float* Aw2 = Vw2 + (size_t)M * HKVn * HDn;
    gemm_mfma<true, 128><<<dim3(DIMn / 128, M / 64, 1), 256, 0, stream>>>(
        x, wq, Qw2, wq, Qw2, DIMn, DIMn);
    gemm_mfma<true, 64><<<dim3((HKVn * HDn) / 64, M / 64, 2), 256, 0, stream>>>(
        x, wk, Kw2, wv, Vw2, DIMn, HKVn * HDn);
    flash_attn_mfma<false><<<Bn * HQn * (Sn / 64), 256, 0, stream>>>(
        Qw2, Kw2, Vw2, fc, fs, sidx, Aw2);
    gemm_mfma<false, 128><<<dim3(DIMn / 128, M / 64, 1), 256, 0, stream>>>(
        Aw2, wo, out, wo, out, DIMn, DIMn);
  }
}